// Round 1
// baseline (778.893 us; speedup 1.0000x reference)
//
#include <hip/hip_runtime.h>

// ---------------- output layout (floats) ----------------
// self_ob : [16384, 608]   @ 0        (enc 0..31 | self_vec 32..95 | fwd 96..351 | rear 352..607)
// tm      : [16384, 5, 64] @ 9961472  (enc 0..31 | teammates 32..63)
// op      : [16384, 6, 64] @ 15204352
// ol      : [16384, 6, 64] @ 21495808
// masks   : [16384, 6, 1]  @ 27787264
// agent   : [16384,16,16,4]@ 27885568
// unmask  : same           @ 44662784
#define TM_BASE     9961472
#define OP_BASE     15204352
#define OL_BASE     21495808
#define MASK_BASE   27787264
#define AGENT_BASE  27885568
#define UNMASK_BASE 44662784

// RES[l] = floor(16 * 2^(0.4*l)) — matches numpy double computation
__device__ __constant__ float c_res[16] = {
  16.f, 21.f, 27.f, 36.f, 48.f, 64.f, 84.f, 111.f,
  147.f, 194.f, 256.f, 337.f, 445.f, 588.f, 776.f, 1024.f};

// ---------------- hashgrid encode ----------------
// thread = (position p, level l); 16 consecutive threads share p -> coalesced writes
__global__ __launch_bounds__(256) void hash_kernel(
    const float* __restrict__ self_pos,
    const float* __restrict__ tm_pos,
    const float* __restrict__ op_pos,
    const float* __restrict__ ol_pos,
    const float* __restrict__ table,
    float* __restrict__ out)
{
  int tid = blockIdx.x * 256 + threadIdx.x;
  int p = tid >> 4;
  int l = tid & 15;
  const float* x;
  int obase;
  if (p < 16384)       {               x = self_pos + p * 3; obase = p * 608 + l * 2; }
  else if (p < 98304)  { int q = p - 16384;  x = tm_pos + q * 3; obase = TM_BASE + q * 64 + l * 2; }
  else if (p < 196608) { int q = p - 98304;  x = op_pos + q * 3; obase = OP_BASE + q * 64 + l * 2; }
  else                 { int q = p - 196608; x = ol_pos + q * 3; obase = OL_BASE + q * 64 + l * 2; }

  float res = c_res[l];
  float w0, w1, w2;
  unsigned u0, u1, u2;
  {
    float xn, s, p0;
    xn = fminf(fmaxf((x[0] + 1.f) * 0.5f, 0.f), 1.f); s = xn * res; p0 = floorf(s); w0 = s - p0; u0 = (unsigned)p0;
    xn = fminf(fmaxf((x[1] + 1.f) * 0.5f, 0.f), 1.f); s = xn * res; p0 = floorf(s); w1 = s - p0; u1 = (unsigned)p0;
    xn = fminf(fmaxf((x[2] + 1.f) * 0.5f, 0.f), 1.f); s = xn * res; p0 = floorf(s); w2 = s - p0; u2 = (unsigned)p0;
  }
  const float* tl = table + l * 32768;   // level slice (T*F = 32768)
  float a0 = 0.f, a1 = 0.f;
  #pragma unroll
  for (int c = 0; c < 8; ++c) {
    unsigned cc0 = u0 + ((c >> 2) & 1);
    unsigned cc1 = u1 + ((c >> 1) & 1);
    unsigned cc2 = u2 + (c & 1);
    unsigned idx = (cc0 ^ (cc1 * 2654435761u) ^ (cc2 * 805459861u)) & 16383u;
    float2 f = *(const float2*)(tl + idx * 2);
    float wc = ((c & 4) ? w0 : 1.f - w0) *
               ((c & 2) ? w1 : 1.f - w1) *
               ((c & 1) ? w2 : 1.f - w2);
    a0 = fmaf(f.x, wc, a0);
    a1 = fmaf(f.y, wc, a1);
  }
  *(float2*)(out + obase) = make_float2(a0, a1);
}

// ---------------- lidar conv stack ----------------
// one wave per (sample b, side); 4 waves / block; side constant per block so
// weight pointers stay scalar (s_load path for the per-fmac weight reads).
#define IN_OFF   0      // [129][9]  input, row 128 = zero pad  (stride 9 -> 4-way max)
#define O1_OFF   1164   // [65][17]  conv1 out, row 64 = pad    (stride 17 -> 2-way, free)
#define O2_OFF   2272   // [33][17]  conv2 out, row 32 = pad
#define LN_OFF   2836   // [256]     conv3 out flat (16B aligned)
#define WAVE_LDS 3104

__global__ __launch_bounds__(256) void lidar_kernel(
    const float* __restrict__ fwdl, const float* __restrict__ rearl,
    const float* __restrict__ fw1, const float* __restrict__ fb1,
    const float* __restrict__ fw2, const float* __restrict__ fb2,
    const float* __restrict__ fw3, const float* __restrict__ fb3,
    const float* __restrict__ fg,  const float* __restrict__ fbe,
    const float* __restrict__ rw1, const float* __restrict__ rb1,
    const float* __restrict__ rw2, const float* __restrict__ rb2,
    const float* __restrict__ rw3, const float* __restrict__ rb3,
    const float* __restrict__ rg,  const float* __restrict__ rbe,
    float* __restrict__ out)
{
  __shared__ float lds[4 * WAVE_LDS];
  const int side = blockIdx.x >> 12;          // 8192 blocks: first half fwd, second rear
  const int wid  = threadIdx.x >> 6;
  const int lane = threadIdx.x & 63;
  const int b    = ((blockIdx.x & 4095) << 2) | wid;

  const float* lid = (side ? rearl : fwdl) + b * 1024;
  const float* w1 = side ? rw1 : fw1;
  const float* b1 = side ? rb1 : fb1;
  const float* w2 = side ? rw2 : fw2;
  const float* b2 = side ? rb2 : fb2;
  const float* w3 = side ? rw3 : fw3;
  const float* b3 = side ? rb3 : fb3;
  const float* g  = side ? rg  : fg;
  const float* be = side ? rbe : fbe;
  float* ld = lds + wid * WAVE_LDS;

  // stage input (B,4,128,2) slice -> in[w][c], c = a*2+p
  #pragma unroll
  for (int k = 0; k < 4; ++k) {
    int off = (k * 64 + lane) * 4;
    float4 v = *(const float4*)(lid + off);
    int a2 = (off >> 8) * 2;
    int w  = (off & 255) >> 1;
    ld[IN_OFF + w * 9 + a2]           = v.x;
    ld[IN_OFF + w * 9 + a2 + 1]       = v.y;
    ld[IN_OFF + (w + 1) * 9 + a2]     = v.z;
    ld[IN_OFF + (w + 1) * 9 + a2 + 1] = v.w;
  }
  if (lane < 9)  ld[IN_OFF + 128 * 9 + lane] = 0.f;
  if (lane < 17) { ld[O1_OFF + 64 * 17 + lane] = 0.f; ld[O2_OFF + 32 * 17 + lane] = 0.f; }
  __syncthreads();

  // conv1: 64 pos x 16ch, kernel 3 stride 2, in ch 8; thread = position
  {
    float acc[16];
    #pragma unroll
    for (int o = 0; o < 16; ++o) acc[o] = b1[o];
    #pragma unroll
    for (int t = 0; t < 3; ++t)
      #pragma unroll
      for (int i = 0; i < 8; ++i) {
        float s = ld[IN_OFF + (2 * lane + t) * 9 + i];
        #pragma unroll
        for (int o = 0; o < 16; ++o) acc[o] = fmaf(s, w1[t * 128 + i * 16 + o], acc[o]);
      }
    #pragma unroll
    for (int o = 0; o < 16; ++o) {
      float v = acc[o];
      ld[O1_OFF + lane * 17 + o] = (v >= 0.f) ? v : 0.01f * v;
    }
  }
  __syncthreads();

  // conv2: 32 pos x 16ch; thread = (pos, ch-half)
  {
    int pos = lane >> 1, ob = (lane & 1) * 8;
    float acc[8];
    #pragma unroll
    for (int o = 0; o < 8; ++o) acc[o] = b2[ob + o];
    #pragma unroll
    for (int t = 0; t < 3; ++t)
      #pragma unroll
      for (int i = 0; i < 16; ++i) {
        float s = ld[O1_OFF + (2 * pos + t) * 17 + i];
        #pragma unroll
        for (int o = 0; o < 8; ++o) acc[o] = fmaf(s, w2[t * 256 + i * 16 + ob + o], acc[o]);
      }
    #pragma unroll
    for (int o = 0; o < 8; ++o) {
      float v = acc[o];
      ld[O2_OFF + pos * 17 + ob + o] = (v >= 0.f) ? v : 0.01f * v;
    }
  }
  __syncthreads();

  // conv3: 16 pos x 16ch, no activation; thread = (pos, ch-quarter)
  {
    int pos = lane >> 2, ob = (lane & 3) * 4;
    float acc[4];
    #pragma unroll
    for (int r = 0; r < 4; ++r) acc[r] = b3[ob + r];
    #pragma unroll
    for (int t = 0; t < 3; ++t)
      #pragma unroll
      for (int i = 0; i < 16; ++i) {
        float s = ld[O2_OFF + (2 * pos + t) * 17 + i];
        #pragma unroll
        for (int r = 0; r < 4; ++r) acc[r] = fmaf(s, w3[t * 256 + i * 16 + ob + r], acc[r]);
      }
    #pragma unroll
    for (int r = 0; r < 4; ++r) ld[LN_OFF + pos * 16 + ob + r] = acc[r];
  }
  __syncthreads();

  // layernorm over 256 + lrelu + store (float4/lane)
  {
    float4 v = *(const float4*)(ld + LN_OFF + lane * 4);
    float s  = v.x + v.y + v.z + v.w;
    float ss = v.x * v.x + v.y * v.y + v.z * v.z + v.w * v.w;
    #pragma unroll
    for (int off = 32; off > 0; off >>= 1) {
      s  += __shfl_xor(s, off);
      ss += __shfl_xor(ss, off);
    }
    float mu  = s * (1.f / 256.f);
    float var = ss * (1.f / 256.f) - mu * mu;
    float rs  = rsqrtf(var + 1e-6f);
    int k = lane * 4;
    float4 gv = *(const float4*)(g + k);
    float4 bv = *(const float4*)(be + k);
    float4 r;
    r.x = (v.x - mu) * rs * gv.x + bv.x; r.x = (r.x >= 0.f) ? r.x : 0.01f * r.x;
    r.y = (v.y - mu) * rs * gv.y + bv.y; r.y = (r.y >= 0.f) ? r.y : 0.01f * r.y;
    r.z = (v.z - mu) * rs * gv.z + bv.z; r.z = (r.z >= 0.f) ? r.z : 0.01f * r.z;
    r.w = (v.w - mu) * rs * gv.w + bv.w; r.w = (r.w >= 0.f) ? r.w : 0.01f * r.w;
    *(float4*)(out + b * 608 + 96 + side * 256 + k) = r;
  }
}

// ---------------- strided row copies (concat fills) ----------------
__global__ __launch_bounds__(256) void copy_rows(
    const float4* __restrict__ src, float4* __restrict__ dst,
    int n4, int lw4, int stride4, int col4)
{
  int tid = blockIdx.x * 256 + threadIdx.x;
  if (tid >= n4) return;
  int row = tid >> lw4;
  int c   = tid & ((1 << lw4) - 1);
  dst[(long long)row * stride4 + col4 + c] = src[tid];
}

extern "C" void kernel_launch(void* const* d_in, const int* in_sizes, int n_in,
                              void* d_out, int out_size, void* d_ws, size_t ws_size,
                              hipStream_t stream)
{
  const float* self_pos   = (const float*)d_in[0];
  const float* tm_pos     = (const float*)d_in[1];
  const float* op_pos     = (const float*)d_in[2];
  const float* ol_pos     = (const float*)d_in[3];
  const float* self_vec   = (const float*)d_in[4];
  const float* fwd_lidar  = (const float*)d_in[5];
  const float* rear_lidar = (const float*)d_in[6];
  const float* teammates  = (const float*)d_in[7];
  const float* opponents  = (const float*)d_in[8];
  const float* opp_last   = (const float*)d_in[9];
  const float* masks      = (const float*)d_in[10];
  const float* agent_map  = (const float*)d_in[11];
  const float* unmasked   = (const float*)d_in[12];
  const float* table      = (const float*)d_in[13];
  float* out = (float*)d_out;

  lidar_kernel<<<8192, 256, 0, stream>>>(fwd_lidar, rear_lidar,
      (const float*)d_in[14], (const float*)d_in[15], (const float*)d_in[16], (const float*)d_in[17],
      (const float*)d_in[18], (const float*)d_in[19], (const float*)d_in[20], (const float*)d_in[21],
      (const float*)d_in[22], (const float*)d_in[23], (const float*)d_in[24], (const float*)d_in[25],
      (const float*)d_in[26], (const float*)d_in[27], (const float*)d_in[28], (const float*)d_in[29],
      out);

  hash_kernel<<<18432, 256, 0, stream>>>(self_pos, tm_pos, op_pos, ol_pos, table, out);

  copy_rows<<<1024, 256, 0, stream>>>((const float4*)self_vec, (float4*)out,
                                      262144, 4, 152, 8);
  copy_rows<<<2560, 256, 0, stream>>>((const float4*)teammates, (float4*)out + TM_BASE / 4,
                                      655360, 3, 16, 8);
  copy_rows<<<3072, 256, 0, stream>>>((const float4*)opponents, (float4*)out + OP_BASE / 4,
                                      786432, 3, 16, 8);
  copy_rows<<<3072, 256, 0, stream>>>((const float4*)opp_last, (float4*)out + OL_BASE / 4,
                                      786432, 3, 16, 8);

  hipMemcpyAsync(out + MASK_BASE,   masks,     98304ull   * sizeof(float), hipMemcpyDeviceToDevice, stream);
  hipMemcpyAsync(out + AGENT_BASE,  agent_map, 16777216ull * sizeof(float), hipMemcpyDeviceToDevice, stream);
  hipMemcpyAsync(out + UNMASK_BASE, unmasked,  16777216ull * sizeof(float), hipMemcpyDeviceToDevice, stream);
}